// Round 3
// baseline (1042.051 us; speedup 1.0000x reference)
//
#include <hip/hip_runtime.h>
#include <stdint.h>

// NARM fused pipeline v7 for MI355X (gfx950).
//   Theory: scan is a barrier-locked latency chain (3 structures all ~2800 cyc/step,
//   both pipes <45%); it also leaves half the machine idle (128 blocks).
//   v7 chunks time (tc=50) and overlaps pipeline stages ACROSS chunks in one fat
//   launch: blocks 0..127 = scan(c), 128..227 = score(c-1), 228..483 = cum(c-2).
//   Dependencies satisfied purely by launch ordering (no intra-launch comms).
//   Also: deferred coalesced h-store (uint2 per thread from LDS, replacing 4
//   scattered 2-byte stores per thread per step).
//   k_prep: zero shared carry slot + cum; cast A1/A2 -> bf16
//   k_fat : role-split scan / score / cum (LDS union, 69.6 KB)

typedef __attribute__((ext_vector_type(8))) short short8;
typedef __attribute__((ext_vector_type(4))) float float4v;

// exec+LDS barrier without the full vmcnt drain of __syncthreads()
#define LDS_BARRIER() asm volatile("s_waitcnt lgkmcnt(0)\n\ts_barrier" ::: "memory")

__device__ inline float bf2f(unsigned short u){
  union { unsigned int i; float f; } v; v.i = ((unsigned int)u) << 16; return v.f;
}
__device__ inline unsigned short f2bf(float f){
  union { float f; unsigned int i; } v; v.f = f;
  unsigned int x = v.i;
  return (unsigned short)((x + 0x7fffu + ((x >> 16) & 1u)) >> 16);
}
// HW packed f32->bf16 RNE (identical rounding to f2bf); no builtin on gfx950
__device__ inline unsigned int cvt_pk_bf16(float a, float b){
  unsigned int r;
  asm("v_cvt_pk_bf16_f32 %0, %1, %2" : "=v"(r) : "v"(a), "v"(b));
  return r;
}
__device__ inline float sigm(float x){ return __builtin_amdgcn_rcpf(1.0f + __expf(-x)); }

// ---------------- K0: prep ----------------
__global__ void k_prep(unsigned short* zs, float* cum,
                       const float* A1, const float* A2, unsigned short* a12)
{
  int i = blockIdx.x * blockDim.x + threadIdx.x;   // grid 512*256 = 131072
  zs[i] = 0;                                        // shared zero carry slot
  cum[i] = 0.0f;
  if (i < 32768) {
    a12[i] = f2bf((i < 16384) ? A1[i] : A2[i - 16384]);
  }
}

// ---------------- fat kernel: scan | score | cum roles ----------------
union __align__(16) LdsU {
  struct { unsigned short hbuf[2][16][136]; unsigned short xbuf[2][16][136]; } scan; // 17408
  struct { unsigned short M1[128][136]; unsigned short M2[128][136]; } sc;           // 69632
  struct { unsigned short hlL[50 * 512]; float scL[4][50]; } cm;                     // 52000
};

__global__ __launch_bounds__(512, 4) void k_fat(
    const float* __restrict__ x,
    const float* __restrict__ Wih_g, const float* __restrict__ Whh_g,
    const float* __restrict__ bih_g, const float* __restrict__ bhh_g,
    const float* __restrict__ Wih_l, const float* __restrict__ Whh_l,
    const float* __restrict__ bih_l, const float* __restrict__ bhh_l,
    const unsigned short* __restrict__ a12, const float* __restrict__ v1,
    const int* __restrict__ lengths,
    unsigned short* __restrict__ hl, unsigned short* __restrict__ hg,
    const unsigned short* __restrict__ zs,
    float* __restrict__ score, float* __restrict__ cum, float* __restrict__ out,
    int scan_t0, int score_t0, int cum_t0)
{
  __shared__ LdsU lds;
  int tid = threadIdx.x;
  int bid = blockIdx.x;

  if (bid < 128) {
    // ================= scan role: chunk [scan_t0, scan_t0+50) =================
    if (scan_t0 < 0) return;
    const int tc = 50;
    int t0 = scan_t0;
    auto& hbuf = lds.scan.hbuf;
    auto& xbuf = lds.scan.xbuf;

    int w = tid >> 6, L = tid & 63, l15 = L & 15, q = L >> 4;
    int gru = bid & 1;                 // 0 = g, 1 = l
    int b0 = (bid >> 1) * 16;
    const float* Wih = gru ? Wih_l : Wih_g;
    const float* Whh = gru ? Whh_l : Whh_g;
    const float* bih = gru ? bih_l : bih_g;
    const float* bhh = gru ? bhh_l : bhh_g;
    unsigned short* myseq = gru ? hl : hg;

    int col = w * 16 + l15;            // this lane's output column

    // register-resident weight B-fragments (fp32 -> bf16 once per launch)
    short8 Wi[3][4], Wh[3][4];
    #pragma unroll
    for (int G = 0; G < 3; G++) {
      int row = G * 128 + col;
      #pragma unroll
      for (int kf = 0; kf < 4; kf++) {
        const float4* p0 = (const float4*)(Wih + (size_t)row * 128 + kf * 32 + q * 8);
        const float4* p1 = (const float4*)(Whh + (size_t)row * 128 + kf * 32 + q * 8);
        float4 a0 = p0[0], a1 = p0[1], b0f = p1[0], b1f = p1[1];
        short8 si, sh;
        si[0]=(short)f2bf(a0.x); si[1]=(short)f2bf(a0.y); si[2]=(short)f2bf(a0.z); si[3]=(short)f2bf(a0.w);
        si[4]=(short)f2bf(a1.x); si[5]=(short)f2bf(a1.y); si[6]=(short)f2bf(a1.z); si[7]=(short)f2bf(a1.w);
        sh[0]=(short)f2bf(b0f.x); sh[1]=(short)f2bf(b0f.y); sh[2]=(short)f2bf(b0f.z); sh[3]=(short)f2bf(b0f.w);
        sh[4]=(short)f2bf(b1f.x); sh[5]=(short)f2bf(b1f.y); sh[6]=(short)f2bf(b1f.z); sh[7]=(short)f2bf(b1f.w);
        Wi[G][kf] = si; Wh[G][kf] = sh;
      }
    }
    float br  = bih[col]       + bhh[col];
    float bz  = bih[128 + col] + bhh[128 + col];
    float bin = bih[256 + col];               // bhh_n stays inside r*( ) per PyTorch GRU
    float bnh = bhh[256 + col];

    // init h from carry: zero slot for chunk 0, else previous chunk's last slice
    const unsigned short* carry = (t0 == 0) ? zs : (myseq + (size_t)(t0 - 1) * 131072);
    float hold[4];
    #pragma unroll
    for (int r = 0; r < 4; r++) {
      int m = q * 4 + r;
      unsigned short u = carry[(size_t)(b0 + m) * 128 + col];
      hold[r] = bf2f(u);
      hbuf[0][m][col] = u;
    }
    // stage x(t0) into xbuf[0]; prefetch x(t0+1) into regs
    int xrow = tid >> 5, xc4 = (tid & 31) * 4;
    size_t hoff = (size_t)b0 * 128 + xrow * 128 + xc4;   // deferred-store offset
    {
      float4 x0 = ((const float4*)(x + ((size_t)t0 * 1024 + b0) * 128))[tid];
      *(uint2*)&xbuf[0][xrow][xc4] = make_uint2(cvt_pk_bf16(x0.x, x0.y), cvt_pk_bf16(x0.z, x0.w));
    }
    float4 xr = ((const float4*)(x + ((size_t)(t0 + 1) * 1024 + b0) * 128))[tid];
    __syncthreads();

    // prologue: x-side chains for step 0 (cx = x(t0)@Wih)
    float4v cx0 = (float4v){0.f,0.f,0.f,0.f}, cx1 = cx0, cx2 = cx0;
    {
      short8 Ax[4];
      #pragma unroll
      for (int kf = 0; kf < 4; kf++) Ax[kf] = *(const short8*)&xbuf[0][l15][kf * 32 + q * 8];
      #pragma unroll
      for (int kf = 0; kf < 4; kf++) cx0 = __builtin_amdgcn_mfma_f32_16x16x32_bf16(Ax[kf], Wi[0][kf], cx0, 0,0,0);
      #pragma unroll
      for (int kf = 0; kf < 4; kf++) cx1 = __builtin_amdgcn_mfma_f32_16x16x32_bf16(Ax[kf], Wi[1][kf], cx1, 0,0,0);
      #pragma unroll
      for (int kf = 0; kf < 4; kf++) cx2 = __builtin_amdgcn_mfma_f32_16x16x32_bf16(Ax[kf], Wi[2][kf], cx2, 0,0,0);
    }
    // commit x(t0+1) into xbuf[1]; prefetch x(t0+2)
    *(uint2*)&xbuf[1][xrow][xc4] = make_uint2(cvt_pk_bf16(xr.x, xr.y), cvt_pk_bf16(xr.z, xr.w));
    xr = ((const float4*)(x + ((size_t)(t0 + 2) * 1024 + b0) * 128))[tid];
    LDS_BARRIER();

    // step s: pin = s&1 holds h(s-1); pout = (s+1)&1 receives h(s).
    //   xbuf[pout] holds x(s+1); xbuf[pin] is dead -> overwritten with x(s+2).
    //   Deferred store: h(s-1) is read back from hbuf[pin] as a coalesced uint2
    //   and written to global (replaces 4 scattered 2-byte stores).
    auto step = [&](int s, int pin, int pout) {
      short8 Ah[4], Axn[4];
      #pragma unroll
      for (int kf = 0; kf < 4; kf++) Ah[kf]  = *(const short8*)&hbuf[pin][l15][kf * 32 + q * 8];
      #pragma unroll
      for (int kf = 0; kf < 4; kf++) Axn[kf] = *(const short8*)&xbuf[pout][l15][kf * 32 + q * 8];

      if (s > 0) {
        uint2 hv = *(const uint2*)&hbuf[pin][xrow][xc4];
        *(uint2*)(myseq + (size_t)(t0 + s - 1) * 131072 + hoff) = hv;
      }

      // critical-path h-chains first
      float4v rh = (float4v){0.f,0.f,0.f,0.f}, zh = rh, nh = rh;
      #pragma unroll
      for (int kf = 0; kf < 4; kf++) rh = __builtin_amdgcn_mfma_f32_16x16x32_bf16(Ah[kf], Wh[0][kf], rh, 0,0,0);
      #pragma unroll
      for (int kf = 0; kf < 4; kf++) zh = __builtin_amdgcn_mfma_f32_16x16x32_bf16(Ah[kf], Wh[1][kf], zh, 0,0,0);
      #pragma unroll
      for (int kf = 0; kf < 4; kf++) nh = __builtin_amdgcn_mfma_f32_16x16x32_bf16(Ah[kf], Wh[2][kf], nh, 0,0,0);

      // background x-chains for step s+1 (drain during gate phase)
      float4v nx0 = (float4v){0.f,0.f,0.f,0.f}, nx1 = nx0, nx2 = nx0;
      #pragma unroll
      for (int kf = 0; kf < 4; kf++) nx0 = __builtin_amdgcn_mfma_f32_16x16x32_bf16(Axn[kf], Wi[0][kf], nx0, 0,0,0);
      #pragma unroll
      for (int kf = 0; kf < 4; kf++) nx1 = __builtin_amdgcn_mfma_f32_16x16x32_bf16(Axn[kf], Wi[1][kf], nx1, 0,0,0);
      #pragma unroll
      for (int kf = 0; kf < 4; kf++) nx2 = __builtin_amdgcn_mfma_f32_16x16x32_bf16(Axn[kf], Wi[2][kf], nx2, 0,0,0);

      // commit prefetched x(s+2) into the dead buffer; issue prefetch of x(s+3)
      *(uint2*)&xbuf[pin][xrow][xc4] = make_uint2(cvt_pk_bf16(xr.x, xr.y), cvt_pk_bf16(xr.z, xr.w));
      {
        int t3 = t0 + (s + 3 < tc ? s + 3 : tc - 1);
        xr = ((const float4*)(x + ((size_t)t3 * 1024 + b0) * 128))[tid];
      }

      // x-side gate constants for THIS step (cx computed one step ago)
      float cr[4], cz[4], cn[4];
      #pragma unroll
      for (int r = 0; r < 4; r++) { cr[r] = cx0[r] + br; cz[r] = cx1[r] + bz; cn[r] = cx2[r] + bin; }

      // gates: shared-rcp sigmoid pair + exp-based tanh
      float hnv[4];
      #pragma unroll
      for (int r = 0; r < 4; r++) {
        float er = __expf(-(rh[r] + cr[r]));
        float ez = __expf(-(zh[r] + cz[r]));
        float pr = 1.0f + er, pz = 1.0f + ez;
        float inv = __builtin_amdgcn_rcpf(pr * pz);
        float rr = pz * inv;                  // = 1/(1+er)
        float zz = pr * inv;                  // = 1/(1+ez)
        float y  = cn[r] + rr * (nh[r] + bnh);
        float em = __expf(-2.0f * y);
        float nn = 2.0f * __builtin_amdgcn_rcpf(1.0f + em) - 1.0f;   // tanh(y)
        hnv[r] = nn + zz * (hold[r] - nn);
        hold[r] = hnv[r];
      }
      unsigned int p01 = cvt_pk_bf16(hnv[0], hnv[1]);
      unsigned int p23 = cvt_pk_bf16(hnv[2], hnv[3]);
      hbuf[pout][q * 4 + 0][col] = (unsigned short)p01;
      hbuf[pout][q * 4 + 1][col] = (unsigned short)(p01 >> 16);
      hbuf[pout][q * 4 + 2][col] = (unsigned short)p23;
      hbuf[pout][q * 4 + 3][col] = (unsigned short)(p23 >> 16);

      cx0 = nx0; cx1 = nx1; cx2 = nx2;
      LDS_BARRIER();
    };

    for (int s = 0; s + 1 < tc; s += 2) { step(s, 0, 1); step(s + 1, 1, 0); }
    // epilogue: store h(tc-1) (tc even -> lives in hbuf[0]); barrier already passed
    {
      uint2 hv = *(const uint2*)&hbuf[tc & 1][xrow][xc4];
      *(uint2*)(myseq + (size_t)(t0 + tc - 1) * 131072 + hoff) = hv;
    }
    return;
  }

  if (bid < 228) {
    // ================= score role: chunk [score_t0, score_t0+50) =================
    if (score_t0 < 0) return;
    int rb = bid - 128;                       // 0..99
    int w = tid >> 6, L = tid & 63;
    int l15 = L & 15, q = L >> 4;
    int s = score_t0 + (rb >> 1);
    int bhalf = (rb & 1) * 512;
    auto& M1 = lds.sc.M1;
    auto& M2 = lds.sc.M2;

    // stage A1, A2 (bf16, pre-cast by k_prep) once: 4096 short8 over 512 thr
    #pragma unroll
    for (int it = 0; it < 4; it++) {
      int f8 = it * 512 + tid;                 // 0..2047
      *(short8*)&M1[f8 >> 4][(f8 & 15) * 8] = *(const short8*)(a12 + (size_t)f8 * 8);
      *(short8*)&M2[f8 >> 4][(f8 & 15) * 8] = *(const short8*)(a12 + 16384 + (size_t)f8 * 8);
    }
    __syncthreads();

    float v1v[8];
    #pragma unroll
    for (int nt = 0; nt < 8; nt++) v1v[nt] = v1[nt * 16 + l15];

    // 4 b-tiles per wave, 1-deep fragment prefetch
    short8 Fl[4], Fg[4], Pl[4], Pg[4];
    {
      size_t base = ((size_t)s * 1024 + bhalf + (size_t)w * 16 + l15) * 128;
      #pragma unroll
      for (int kf = 0; kf < 4; kf++) {
        Fl[kf] = *(const short8*)(hl + base + kf * 32 + q * 8);
        Fg[kf] = *(const short8*)(hg + base + kf * 32 + q * 8);
      }
    }
    #pragma unroll
    for (int it = 0; it < 4; it++) {
      int b0s = bhalf + (it * 8 + w) * 16;
      if (it + 1 < 4) {
        size_t base = ((size_t)s * 1024 + bhalf + (size_t)((it + 1) * 8 + w) * 16 + l15) * 128;
        #pragma unroll
        for (int kf = 0; kf < 4; kf++) {
          Pl[kf] = *(const short8*)(hl + base + kf * 32 + q * 8);
          Pg[kf] = *(const short8*)(hg + base + kf * 32 + q * 8);
        }
      }
      float4v acc[8];
      #pragma unroll
      for (int nt = 0; nt < 8; nt++) {
        float4v a = (float4v){0.f, 0.f, 0.f, 0.f};
        #pragma unroll
        for (int kf = 0; kf < 4; kf++)
          a = __builtin_amdgcn_mfma_f32_16x16x32_bf16(
              Fl[kf], *(const short8*)&M1[nt * 16 + l15][kf * 32 + q * 8], a, 0, 0, 0);
        #pragma unroll
        for (int kf = 0; kf < 4; kf++)
          a = __builtin_amdgcn_mfma_f32_16x16x32_bf16(
              Fg[kf], *(const short8*)&M2[nt * 16 + l15][kf * 32 + q * 8], a, 0, 0, 0);
        acc[nt] = a;
      }
      float p4[4];
      #pragma unroll
      for (int r = 0; r < 4; r++) {
        float sum = 0.f;
        #pragma unroll
        for (int nt = 0; nt < 8; nt++) sum += v1v[nt] * sigm(acc[nt][r]);
        sum += __shfl_xor(sum, 1, 16);
        sum += __shfl_xor(sum, 2, 16);
        sum += __shfl_xor(sum, 4, 16);
        sum += __shfl_xor(sum, 8, 16);
        p4[r] = sum;
      }
      if (l15 == 0) {
        #pragma unroll
        for (int r = 0; r < 4; r++)
          score[(size_t)(b0s + q * 4 + r) * 200 + s] = p4[r];   // layout [b][200]
      }
      #pragma unroll
      for (int kf = 0; kf < 4; kf++) { Fl[kf] = Pl[kf]; Fg[kf] = Pg[kf]; }
    }
    return;
  }

  // ================= cum role: chunk [cum_t0, cum_t0+50) =================
  if (cum_t0 < 0) return;
  {
    int rb = bid - 228;                       // 0..255
    int b4 = tid >> 7, j = tid & 127;
    int b0c = rb * 4;
    int b = b0c + b4;
    int t0c = cum_t0;

    float c = cum[(size_t)b * 128 + j];
    int cap0 = lengths[b] - 4;                // capture window [cap0, cap0+3] in [0,199]

    // preload the (<=4) h_g capture values that fall in this chunk
    float hgv[4];
    #pragma unroll
    for (int d = 0; d < 4; d++) {
      int sl = cap0 + d - t0c;
      hgv[d] = (sl >= 0 && sl < 50) ? bf2f(hg[((size_t)(cap0 + d) * 1024 + b) * 128 + j]) : 0.f;
    }

    // stage hl rows [t0c, t0c+50) for 4 batch rows: coalesced short8
    for (int f8 = tid; f8 < 50 * 64; f8 += 512) {
      int sl = f8 >> 6, r8 = f8 & 63;
      *(short8*)&lds.cm.hlL[(size_t)f8 * 8] =
          *(const short8*)(hl + ((size_t)(t0c + sl) * 1024 + b0c) * 128 + r8 * 8);
    }
    // stage score rows (contiguous per b: layout [b][200])
    for (int i = tid; i < 4 * 50; i += 512) {
      int bb = i / 50, sl = i - bb * 50;
      lds.cm.scL[bb][sl] = score[(size_t)(b0c + bb) * 200 + t0c + sl];
    }
    __syncthreads();

    int base = b4 * 128 + j;
    for (int sl = 0; sl < 50; sl += 5) {
      float h[5], scv[5];
      #pragma unroll
      for (int k = 0; k < 5; k++) {
        h[k] = bf2f(lds.cm.hlL[(size_t)(sl + k) * 512 + base]);
        scv[k] = lds.cm.scL[b4][sl + k];
      }
      #pragma unroll
      for (int k = 0; k < 5; k++) {
        c += scv[k] * h[k];
        int d = (t0c + sl + k) - cap0;
        if ((unsigned)d < 4u)
          out[((size_t)b * 4 + d) * 128 + j] = c + hgv[d];
      }
    }
    cum[(size_t)b * 128 + j] = c;
  }
}

// ---------------- launch ----------------
extern "C" void kernel_launch(void* const* d_in, const int* in_sizes, int n_in,
                              void* d_out, int out_size, void* d_ws, size_t ws_size,
                              hipStream_t stream)
{
  const float* x     = (const float*)d_in[0];
  const int* lengths = (const int*)d_in[1];
  const float* Wih_g = (const float*)d_in[2];
  const float* Whh_g = (const float*)d_in[3];
  const float* bih_g = (const float*)d_in[4];
  const float* bhh_g = (const float*)d_in[5];
  const float* Wih_l = (const float*)d_in[6];
  const float* Whh_l = (const float*)d_in[7];
  const float* bih_l = (const float*)d_in[8];
  const float* bhh_l = (const float*)d_in[9];
  const float* A1    = (const float*)d_in[10];
  const float* A2    = (const float*)d_in[11];
  const float* v1    = (const float*)d_in[12];
  float* out = (float*)d_out;

  const int TC = 50;
  char* wsb = (char*)d_ws;
  size_t o = 0;
  unsigned short* a12 = (unsigned short*)(wsb + o); o += 65536;
  float* cum          = (float*)(wsb + o);          o += 524288;
  unsigned short* zs  = (unsigned short*)(wsb + o); o += 262144;
  unsigned short* hl  = (unsigned short*)(wsb + o); o += (size_t)200 * 1024 * 128 * 2;
  unsigned short* hg  = (unsigned short*)(wsb + o); o += (size_t)200 * 1024 * 128 * 2;
  float* score        = (float*)(wsb + o);          o += (size_t)1024 * 200 * 4;
  if (o > ws_size) return;

  k_prep<<<512, 256, 0, stream>>>(zs, cum, A1, A2, a12);

  // pipeline: launch L runs scan(L), score(L-1), cum(L-2) concurrently
  for (int Lh = 0; Lh < 6; Lh++) {
    int st0 = (Lh < 4) ? Lh * TC : -1;
    int sc0 = (Lh >= 1 && Lh <= 4) ? (Lh - 1) * TC : -1;
    int cu0 = (Lh >= 2) ? (Lh - 2) * TC : -1;
    k_fat<<<484, 512, 0, stream>>>(x, Wih_g, Whh_g, bih_g, bhh_g,
                                   Wih_l, Whh_l, bih_l, bhh_l,
                                   a12, v1, lengths, hl, hg, zs,
                                   score, cum, out, st0, sc0, cu0);
  }
}

// Round 4
// 421.234 us; speedup vs baseline: 2.4738x; 2.4738x over previous
//
#include <hip/hip_runtime.h>
#include <stdint.h>

// NARM fused pipeline v8 for MI355X (gfx950).
//   v7 post-mortem: __launch_bounds__(512,4) clamped VGPRs 124->64, spilling the
//   register-resident weight fragments (96 VGPRs) to scratch -> 4x scan slowdown
//   (MfmaUtil 0.08%, VALUBusy 0.13%, +52MB spill writes). The overlap structure
//   was never actually exercised.
//   v8 = v7 with __launch_bounds__(512,2) (v6's bound -> 124 VGPRs, no spill).
//   Pipeline: launch L runs scan(L) on blocks 0..127, score(L-1) on 128..227,
//   cum(L-2) on 228..483. Dependencies satisfied by launch ordering.

typedef __attribute__((ext_vector_type(8))) short short8;
typedef __attribute__((ext_vector_type(4))) float float4v;

// exec+LDS barrier without the full vmcnt drain of __syncthreads()
#define LDS_BARRIER() asm volatile("s_waitcnt lgkmcnt(0)\n\ts_barrier" ::: "memory")

__device__ inline float bf2f(unsigned short u){
  union { unsigned int i; float f; } v; v.i = ((unsigned int)u) << 16; return v.f;
}
__device__ inline unsigned short f2bf(float f){
  union { float f; unsigned int i; } v; v.f = f;
  unsigned int x = v.i;
  return (unsigned short)((x + 0x7fffu + ((x >> 16) & 1u)) >> 16);
}
// HW packed f32->bf16 RNE (identical rounding to f2bf); no builtin on gfx950
__device__ inline unsigned int cvt_pk_bf16(float a, float b){
  unsigned int r;
  asm("v_cvt_pk_bf16_f32 %0, %1, %2" : "=v"(r) : "v"(a), "v"(b));
  return r;
}
__device__ inline float sigm(float x){ return __builtin_amdgcn_rcpf(1.0f + __expf(-x)); }

// ---------------- K0: prep ----------------
__global__ void k_prep(unsigned short* zs, float* cum,
                       const float* A1, const float* A2, unsigned short* a12)
{
  int i = blockIdx.x * blockDim.x + threadIdx.x;   // grid 512*256 = 131072
  zs[i] = 0;                                        // shared zero carry slot
  cum[i] = 0.0f;
  if (i < 32768) {
    a12[i] = f2bf((i < 16384) ? A1[i] : A2[i - 16384]);
  }
}

// ---------------- fat kernel: scan | score | cum roles ----------------
union __align__(16) LdsU {
  struct { unsigned short hbuf[2][16][136]; unsigned short xbuf[2][16][136]; } scan; // 17408
  struct { unsigned short M1[128][136]; unsigned short M2[128][136]; } sc;           // 69632
  struct { unsigned short hlL[50 * 512]; float scL[4][50]; } cm;                     // 52000
};

__global__ __launch_bounds__(512, 2) void k_fat(
    const float* __restrict__ x,
    const float* __restrict__ Wih_g, const float* __restrict__ Whh_g,
    const float* __restrict__ bih_g, const float* __restrict__ bhh_g,
    const float* __restrict__ Wih_l, const float* __restrict__ Whh_l,
    const float* __restrict__ bih_l, const float* __restrict__ bhh_l,
    const unsigned short* __restrict__ a12, const float* __restrict__ v1,
    const int* __restrict__ lengths,
    unsigned short* __restrict__ hl, unsigned short* __restrict__ hg,
    const unsigned short* __restrict__ zs,
    float* __restrict__ score, float* __restrict__ cum, float* __restrict__ out,
    int scan_t0, int score_t0, int cum_t0)
{
  __shared__ LdsU lds;
  int tid = threadIdx.x;
  int bid = blockIdx.x;

  if (bid < 128) {
    // ================= scan role: chunk [scan_t0, scan_t0+50) =================
    if (scan_t0 < 0) return;
    const int tc = 50;
    int t0 = scan_t0;
    auto& hbuf = lds.scan.hbuf;
    auto& xbuf = lds.scan.xbuf;

    int w = tid >> 6, L = tid & 63, l15 = L & 15, q = L >> 4;
    int gru = bid & 1;                 // 0 = g, 1 = l
    int b0 = (bid >> 1) * 16;
    const float* Wih = gru ? Wih_l : Wih_g;
    const float* Whh = gru ? Whh_l : Whh_g;
    const float* bih = gru ? bih_l : bih_g;
    const float* bhh = gru ? bhh_l : bhh_g;
    unsigned short* myseq = gru ? hl : hg;

    int col = w * 16 + l15;            // this lane's output column

    // register-resident weight B-fragments (fp32 -> bf16 once per launch)
    short8 Wi[3][4], Wh[3][4];
    #pragma unroll
    for (int G = 0; G < 3; G++) {
      int row = G * 128 + col;
      #pragma unroll
      for (int kf = 0; kf < 4; kf++) {
        const float4* p0 = (const float4*)(Wih + (size_t)row * 128 + kf * 32 + q * 8);
        const float4* p1 = (const float4*)(Whh + (size_t)row * 128 + kf * 32 + q * 8);
        float4 a0 = p0[0], a1 = p0[1], b0f = p1[0], b1f = p1[1];
        short8 si, sh;
        si[0]=(short)f2bf(a0.x); si[1]=(short)f2bf(a0.y); si[2]=(short)f2bf(a0.z); si[3]=(short)f2bf(a0.w);
        si[4]=(short)f2bf(a1.x); si[5]=(short)f2bf(a1.y); si[6]=(short)f2bf(a1.z); si[7]=(short)f2bf(a1.w);
        sh[0]=(short)f2bf(b0f.x); sh[1]=(short)f2bf(b0f.y); sh[2]=(short)f2bf(b0f.z); sh[3]=(short)f2bf(b0f.w);
        sh[4]=(short)f2bf(b1f.x); sh[5]=(short)f2bf(b1f.y); sh[6]=(short)f2bf(b1f.z); sh[7]=(short)f2bf(b1f.w);
        Wi[G][kf] = si; Wh[G][kf] = sh;
      }
    }
    float br  = bih[col]       + bhh[col];
    float bz  = bih[128 + col] + bhh[128 + col];
    float bin = bih[256 + col];               // bhh_n stays inside r*( ) per PyTorch GRU
    float bnh = bhh[256 + col];

    // init h from carry: zero slot for chunk 0, else previous chunk's last slice
    const unsigned short* carry = (t0 == 0) ? zs : (myseq + (size_t)(t0 - 1) * 131072);
    float hold[4];
    #pragma unroll
    for (int r = 0; r < 4; r++) {
      int m = q * 4 + r;
      unsigned short u = carry[(size_t)(b0 + m) * 128 + col];
      hold[r] = bf2f(u);
      hbuf[0][m][col] = u;
    }
    // stage x(t0) into xbuf[0]; prefetch x(t0+1) into regs
    int xrow = tid >> 5, xc4 = (tid & 31) * 4;
    size_t hoff = (size_t)b0 * 128 + xrow * 128 + xc4;   // deferred-store offset
    {
      float4 x0 = ((const float4*)(x + ((size_t)t0 * 1024 + b0) * 128))[tid];
      *(uint2*)&xbuf[0][xrow][xc4] = make_uint2(cvt_pk_bf16(x0.x, x0.y), cvt_pk_bf16(x0.z, x0.w));
    }
    float4 xr = ((const float4*)(x + ((size_t)(t0 + 1) * 1024 + b0) * 128))[tid];
    __syncthreads();

    // prologue: x-side chains for step 0 (cx = x(t0)@Wih)
    float4v cx0 = (float4v){0.f,0.f,0.f,0.f}, cx1 = cx0, cx2 = cx0;
    {
      short8 Ax[4];
      #pragma unroll
      for (int kf = 0; kf < 4; kf++) Ax[kf] = *(const short8*)&xbuf[0][l15][kf * 32 + q * 8];
      #pragma unroll
      for (int kf = 0; kf < 4; kf++) cx0 = __builtin_amdgcn_mfma_f32_16x16x32_bf16(Ax[kf], Wi[0][kf], cx0, 0,0,0);
      #pragma unroll
      for (int kf = 0; kf < 4; kf++) cx1 = __builtin_amdgcn_mfma_f32_16x16x32_bf16(Ax[kf], Wi[1][kf], cx1, 0,0,0);
      #pragma unroll
      for (int kf = 0; kf < 4; kf++) cx2 = __builtin_amdgcn_mfma_f32_16x16x32_bf16(Ax[kf], Wi[2][kf], cx2, 0,0,0);
    }
    // commit x(t0+1) into xbuf[1]; prefetch x(t0+2)
    *(uint2*)&xbuf[1][xrow][xc4] = make_uint2(cvt_pk_bf16(xr.x, xr.y), cvt_pk_bf16(xr.z, xr.w));
    xr = ((const float4*)(x + ((size_t)(t0 + 2) * 1024 + b0) * 128))[tid];
    LDS_BARRIER();

    // step s: pin = s&1 holds h(s-1); pout = (s+1)&1 receives h(s).
    //   xbuf[pout] holds x(s+1); xbuf[pin] is dead -> overwritten with x(s+2).
    //   Deferred store: h(s-1) is read back from hbuf[pin] as a coalesced uint2
    //   and written to global (replaces 4 scattered 2-byte stores).
    auto step = [&](int s, int pin, int pout) {
      short8 Ah[4], Axn[4];
      #pragma unroll
      for (int kf = 0; kf < 4; kf++) Ah[kf]  = *(const short8*)&hbuf[pin][l15][kf * 32 + q * 8];
      #pragma unroll
      for (int kf = 0; kf < 4; kf++) Axn[kf] = *(const short8*)&xbuf[pout][l15][kf * 32 + q * 8];

      if (s > 0) {
        uint2 hv = *(const uint2*)&hbuf[pin][xrow][xc4];
        *(uint2*)(myseq + (size_t)(t0 + s - 1) * 131072 + hoff) = hv;
      }

      // critical-path h-chains first
      float4v rh = (float4v){0.f,0.f,0.f,0.f}, zh = rh, nh = rh;
      #pragma unroll
      for (int kf = 0; kf < 4; kf++) rh = __builtin_amdgcn_mfma_f32_16x16x32_bf16(Ah[kf], Wh[0][kf], rh, 0,0,0);
      #pragma unroll
      for (int kf = 0; kf < 4; kf++) zh = __builtin_amdgcn_mfma_f32_16x16x32_bf16(Ah[kf], Wh[1][kf], zh, 0,0,0);
      #pragma unroll
      for (int kf = 0; kf < 4; kf++) nh = __builtin_amdgcn_mfma_f32_16x16x32_bf16(Ah[kf], Wh[2][kf], nh, 0,0,0);

      // background x-chains for step s+1 (drain during gate phase)
      float4v nx0 = (float4v){0.f,0.f,0.f,0.f}, nx1 = nx0, nx2 = nx0;
      #pragma unroll
      for (int kf = 0; kf < 4; kf++) nx0 = __builtin_amdgcn_mfma_f32_16x16x32_bf16(Axn[kf], Wi[0][kf], nx0, 0,0,0);
      #pragma unroll
      for (int kf = 0; kf < 4; kf++) nx1 = __builtin_amdgcn_mfma_f32_16x16x32_bf16(Axn[kf], Wi[1][kf], nx1, 0,0,0);
      #pragma unroll
      for (int kf = 0; kf < 4; kf++) nx2 = __builtin_amdgcn_mfma_f32_16x16x32_bf16(Axn[kf], Wi[2][kf], nx2, 0,0,0);

      // commit prefetched x(s+2) into the dead buffer; issue prefetch of x(s+3)
      *(uint2*)&xbuf[pin][xrow][xc4] = make_uint2(cvt_pk_bf16(xr.x, xr.y), cvt_pk_bf16(xr.z, xr.w));
      {
        int t3 = t0 + (s + 3 < tc ? s + 3 : tc - 1);
        xr = ((const float4*)(x + ((size_t)t3 * 1024 + b0) * 128))[tid];
      }

      // x-side gate constants for THIS step (cx computed one step ago)
      float cr[4], cz[4], cn[4];
      #pragma unroll
      for (int r = 0; r < 4; r++) { cr[r] = cx0[r] + br; cz[r] = cx1[r] + bz; cn[r] = cx2[r] + bin; }

      // gates: shared-rcp sigmoid pair + exp-based tanh
      float hnv[4];
      #pragma unroll
      for (int r = 0; r < 4; r++) {
        float er = __expf(-(rh[r] + cr[r]));
        float ez = __expf(-(zh[r] + cz[r]));
        float pr = 1.0f + er, pz = 1.0f + ez;
        float inv = __builtin_amdgcn_rcpf(pr * pz);
        float rr = pz * inv;                  // = 1/(1+er)
        float zz = pr * inv;                  // = 1/(1+ez)
        float y  = cn[r] + rr * (nh[r] + bnh);
        float em = __expf(-2.0f * y);
        float nn = 2.0f * __builtin_amdgcn_rcpf(1.0f + em) - 1.0f;   // tanh(y)
        hnv[r] = nn + zz * (hold[r] - nn);
        hold[r] = hnv[r];
      }
      unsigned int p01 = cvt_pk_bf16(hnv[0], hnv[1]);
      unsigned int p23 = cvt_pk_bf16(hnv[2], hnv[3]);
      hbuf[pout][q * 4 + 0][col] = (unsigned short)p01;
      hbuf[pout][q * 4 + 1][col] = (unsigned short)(p01 >> 16);
      hbuf[pout][q * 4 + 2][col] = (unsigned short)p23;
      hbuf[pout][q * 4 + 3][col] = (unsigned short)(p23 >> 16);

      cx0 = nx0; cx1 = nx1; cx2 = nx2;
      LDS_BARRIER();
    };

    for (int s = 0; s + 1 < tc; s += 2) { step(s, 0, 1); step(s + 1, 1, 0); }
    // epilogue: store h(tc-1) (tc even -> lives in hbuf[0]); barrier already passed
    {
      uint2 hv = *(const uint2*)&hbuf[tc & 1][xrow][xc4];
      *(uint2*)(myseq + (size_t)(t0 + tc - 1) * 131072 + hoff) = hv;
    }
    return;
  }

  if (bid < 228) {
    // ================= score role: chunk [score_t0, score_t0+50) =================
    if (score_t0 < 0) return;
    int rb = bid - 128;                       // 0..99
    int w = tid >> 6, L = tid & 63;
    int l15 = L & 15, q = L >> 4;
    int s = score_t0 + (rb >> 1);
    int bhalf = (rb & 1) * 512;
    auto& M1 = lds.sc.M1;
    auto& M2 = lds.sc.M2;

    // stage A1, A2 (bf16, pre-cast by k_prep) once: 4096 short8 over 512 thr
    #pragma unroll
    for (int it = 0; it < 4; it++) {
      int f8 = it * 512 + tid;                 // 0..2047
      *(short8*)&M1[f8 >> 4][(f8 & 15) * 8] = *(const short8*)(a12 + (size_t)f8 * 8);
      *(short8*)&M2[f8 >> 4][(f8 & 15) * 8] = *(const short8*)(a12 + 16384 + (size_t)f8 * 8);
    }
    __syncthreads();

    float v1v[8];
    #pragma unroll
    for (int nt = 0; nt < 8; nt++) v1v[nt] = v1[nt * 16 + l15];

    // 4 b-tiles per wave, 1-deep fragment prefetch
    short8 Fl[4], Fg[4], Pl[4], Pg[4];
    {
      size_t base = ((size_t)s * 1024 + bhalf + (size_t)w * 16 + l15) * 128;
      #pragma unroll
      for (int kf = 0; kf < 4; kf++) {
        Fl[kf] = *(const short8*)(hl + base + kf * 32 + q * 8);
        Fg[kf] = *(const short8*)(hg + base + kf * 32 + q * 8);
      }
    }
    #pragma unroll
    for (int it = 0; it < 4; it++) {
      int b0s = bhalf + (it * 8 + w) * 16;
      if (it + 1 < 4) {
        size_t base = ((size_t)s * 1024 + bhalf + (size_t)((it + 1) * 8 + w) * 16 + l15) * 128;
        #pragma unroll
        for (int kf = 0; kf < 4; kf++) {
          Pl[kf] = *(const short8*)(hl + base + kf * 32 + q * 8);
          Pg[kf] = *(const short8*)(hg + base + kf * 32 + q * 8);
        }
      }
      float4v acc[8];
      #pragma unroll
      for (int nt = 0; nt < 8; nt++) {
        float4v a = (float4v){0.f, 0.f, 0.f, 0.f};
        #pragma unroll
        for (int kf = 0; kf < 4; kf++)
          a = __builtin_amdgcn_mfma_f32_16x16x32_bf16(
              Fl[kf], *(const short8*)&M1[nt * 16 + l15][kf * 32 + q * 8], a, 0, 0, 0);
        #pragma unroll
        for (int kf = 0; kf < 4; kf++)
          a = __builtin_amdgcn_mfma_f32_16x16x32_bf16(
              Fg[kf], *(const short8*)&M2[nt * 16 + l15][kf * 32 + q * 8], a, 0, 0, 0);
        acc[nt] = a;
      }
      float p4[4];
      #pragma unroll
      for (int r = 0; r < 4; r++) {
        float sum = 0.f;
        #pragma unroll
        for (int nt = 0; nt < 8; nt++) sum += v1v[nt] * sigm(acc[nt][r]);
        sum += __shfl_xor(sum, 1, 16);
        sum += __shfl_xor(sum, 2, 16);
        sum += __shfl_xor(sum, 4, 16);
        sum += __shfl_xor(sum, 8, 16);
        p4[r] = sum;
      }
      if (l15 == 0) {
        #pragma unroll
        for (int r = 0; r < 4; r++)
          score[(size_t)(b0s + q * 4 + r) * 200 + s] = p4[r];   // layout [b][200]
      }
      #pragma unroll
      for (int kf = 0; kf < 4; kf++) { Fl[kf] = Pl[kf]; Fg[kf] = Pg[kf]; }
    }
    return;
  }

  // ================= cum role: chunk [cum_t0, cum_t0+50) =================
  if (cum_t0 < 0) return;
  {
    int rb = bid - 228;                       // 0..255
    int b4 = tid >> 7, j = tid & 127;
    int b0c = rb * 4;
    int b = b0c + b4;
    int t0c = cum_t0;

    float c = cum[(size_t)b * 128 + j];
    int cap0 = lengths[b] - 4;                // capture window [cap0, cap0+3] in [0,199]

    // preload the (<=4) h_g capture values that fall in this chunk
    float hgv[4];
    #pragma unroll
    for (int d = 0; d < 4; d++) {
      int sl = cap0 + d - t0c;
      hgv[d] = (sl >= 0 && sl < 50) ? bf2f(hg[((size_t)(cap0 + d) * 1024 + b) * 128 + j]) : 0.f;
    }

    // stage hl rows [t0c, t0c+50) for 4 batch rows: coalesced short8
    for (int f8 = tid; f8 < 50 * 64; f8 += 512) {
      int sl = f8 >> 6, r8 = f8 & 63;
      *(short8*)&lds.cm.hlL[(size_t)f8 * 8] =
          *(const short8*)(hl + ((size_t)(t0c + sl) * 1024 + b0c) * 128 + r8 * 8);
    }
    // stage score rows (contiguous per b: layout [b][200])
    for (int i = tid; i < 4 * 50; i += 512) {
      int bb = i / 50, sl = i - bb * 50;
      lds.cm.scL[bb][sl] = score[(size_t)(b0c + bb) * 200 + t0c + sl];
    }
    __syncthreads();

    int base = b4 * 128 + j;
    for (int sl = 0; sl < 50; sl += 5) {
      float h[5], scv[5];
      #pragma unroll
      for (int k = 0; k < 5; k++) {
        h[k] = bf2f(lds.cm.hlL[(size_t)(sl + k) * 512 + base]);
        scv[k] = lds.cm.scL[b4][sl + k];
      }
      #pragma unroll
      for (int k = 0; k < 5; k++) {
        c += scv[k] * h[k];
        int d = (t0c + sl + k) - cap0;
        if ((unsigned)d < 4u)
          out[((size_t)b * 4 + d) * 128 + j] = c + hgv[d];
      }
    }
    cum[(size_t)b * 128 + j] = c;
  }
}

// ---------------- launch ----------------
extern "C" void kernel_launch(void* const* d_in, const int* in_sizes, int n_in,
                              void* d_out, int out_size, void* d_ws, size_t ws_size,
                              hipStream_t stream)
{
  const float* x     = (const float*)d_in[0];
  const int* lengths = (const int*)d_in[1];
  const float* Wih_g = (const float*)d_in[2];
  const float* Whh_g = (const float*)d_in[3];
  const float* bih_g = (const float*)d_in[4];
  const float* bhh_g = (const float*)d_in[5];
  const float* Wih_l = (const float*)d_in[6];
  const float* Whh_l = (const float*)d_in[7];
  const float* bih_l = (const float*)d_in[8];
  const float* bhh_l = (const float*)d_in[9];
  const float* A1    = (const float*)d_in[10];
  const float* A2    = (const float*)d_in[11];
  const float* v1    = (const float*)d_in[12];
  float* out = (float*)d_out;

  const int TC = 50;
  char* wsb = (char*)d_ws;
  size_t o = 0;
  unsigned short* a12 = (unsigned short*)(wsb + o); o += 65536;
  float* cum          = (float*)(wsb + o);          o += 524288;
  unsigned short* zs  = (unsigned short*)(wsb + o); o += 262144;
  unsigned short* hl  = (unsigned short*)(wsb + o); o += (size_t)200 * 1024 * 128 * 2;
  unsigned short* hg  = (unsigned short*)(wsb + o); o += (size_t)200 * 1024 * 128 * 2;
  float* score        = (float*)(wsb + o);          o += (size_t)1024 * 200 * 4;
  if (o > ws_size) return;

  k_prep<<<512, 256, 0, stream>>>(zs, cum, A1, A2, a12);

  // pipeline: launch L runs scan(L), score(L-1), cum(L-2) concurrently
  for (int Lh = 0; Lh < 6; Lh++) {
    int st0 = (Lh < 4) ? Lh * TC : -1;
    int sc0 = (Lh >= 1 && Lh <= 4) ? (Lh - 1) * TC : -1;
    int cu0 = (Lh >= 2) ? (Lh - 2) * TC : -1;
    k_fat<<<484, 512, 0, stream>>>(x, Wih_g, Whh_g, bih_g, bhh_g,
                                   Wih_l, Whh_l, bih_l, bhh_l,
                                   a12, v1, lengths, hl, hg, zs,
                                   score, cum, out, st0, sc0, cu0);
  }
}

// Round 6
// 398.803 us; speedup vs baseline: 2.6129x; 1.0562x over previous
//
#include <hip/hip_runtime.h>
#include <stdint.h>

// NARM fused pipeline v10 for MI355X (gfx950).
//   v9 post-mortem: cooperative spin-flag kernel silently failed (absmax ~ max|ref|)
//   -> abandon intra-kernel sync; return to v8's PROVEN multi-launch role-split.
//   v8 measured: riders are free (scan+riders == scan-only, 73.5 vs 73.4us), but
//   per-chunk init ~18us x4 + 2 drain launches ate the win.
//   v10: tc=100 (2 chunks, init paid 2x; 5 launches total) + bf16 weight stash
//   (k_prep pre-casts all 4 weight matrices into lane-contiguous MFMA B-fragments;
//   scan init = 24 coalesced 16B loads, no fp32 loads / no f2bf casts).
//     L1: scan(0)             grid 128
//     L2: scan(1)+score(0)    grid 328 (riders hidden under scan)
//     L3: score(1)+cum(0)     grid 584
//     L4: cum(1)              grid 584
//   Roles: bid<128 scan | 128..327 score | 328..583 cum.

typedef __attribute__((ext_vector_type(8))) short short8;
typedef __attribute__((ext_vector_type(4))) float float4v;

// exec+LDS barrier without the full vmcnt drain of __syncthreads()
#define LDS_BARRIER() asm volatile("s_waitcnt lgkmcnt(0)\n\ts_barrier" ::: "memory")

__device__ inline float bf2f(unsigned short u){
  union { unsigned int i; float f; } v; v.i = ((unsigned int)u) << 16; return v.f;
}
__device__ inline unsigned short f2bf(float f){
  union { float f; unsigned int i; } v; v.f = f;
  unsigned int x = v.i;
  return (unsigned short)((x + 0x7fffu + ((x >> 16) & 1u)) >> 16);
}
// HW packed f32->bf16 RNE (identical rounding to f2bf); no builtin on gfx950
__device__ inline unsigned int cvt_pk_bf16(float a, float b){
  unsigned int r;
  asm("v_cvt_pk_bf16_f32 %0, %1, %2" : "=v"(r) : "v"(a), "v"(b));
  return r;
}
__device__ inline float sigm(float x){ return __builtin_amdgcn_rcpf(1.0f + __expf(-x)); }

// ---------------- K0: prep ----------------
// grid 768*256 = 196608 threads.
//   cum[131072] = 0; a12 = bf16(A1,A2);
//   wst: 48 fragments x 512 threads x 8 bf16. Fragment f = (gm*3+G)*4+kf,
//   gm: 0=Wih_g 1=Whh_g 2=Wih_l 3=Whh_l. Element i=(f<<12)|(t<<3)|e holds
//   bf16(src[(G*128 + (t>>6)*16 + (t&15))*128 + kf*32 + ((t>>4)&3)*8 + e])
//   so scan thread t loads fragment (G,kf) as one coalesced 16B read at wst+(f<<12)+t*8.
__global__ void k_prep(float* cum, const float* A1, const float* A2, unsigned short* a12,
                       const float* Wih_g, const float* Whh_g,
                       const float* Wih_l, const float* Whh_l, unsigned short* wst)
{
  int i = blockIdx.x * blockDim.x + threadIdx.x;
  if (i < 131072) cum[i] = 0.0f;
  if (i < 32768) a12[i] = f2bf((i < 16384) ? A1[i] : A2[i - 16384]);
  {
    int f = i >> 12;                 // 0..47
    int r = i & 4095;
    int t = r >> 3, e = r & 7;
    int l15 = t & 15, q = (t >> 4) & 3, wv = t >> 6;
    int col = wv * 16 + l15;
    int kf = f & 3, g3 = f >> 2;     // g3 = gm*3+G
    int G = g3 % 3, gm = g3 / 3;
    const float* src = (gm == 0) ? Wih_g : (gm == 1) ? Whh_g : (gm == 2) ? Wih_l : Whh_l;
    int row = G * 128 + col;
    int k = kf * 32 + q * 8 + e;
    wst[i] = f2bf(src[(size_t)row * 128 + k]);
  }
}

// ---------------- fat kernel: scan | score | cum roles ----------------
union __align__(16) LdsU {
  struct { unsigned short hbuf[2][16][136]; unsigned short xbuf[2][16][136]; } scan; // 17408
  struct { unsigned short M1[128][136]; unsigned short M2[128][136]; } sc;           // 69632
  struct { unsigned short hlL[50 * 512]; float scL[4][50]; } cm;                     // 52000
};

__global__ __launch_bounds__(512, 2) void k_fat(
    const float* __restrict__ x,
    const float* __restrict__ bih_g, const float* __restrict__ bhh_g,
    const float* __restrict__ bih_l, const float* __restrict__ bhh_l,
    const unsigned short* __restrict__ wst,
    const unsigned short* __restrict__ a12, const float* __restrict__ v1,
    const int* __restrict__ lengths,
    unsigned short* __restrict__ hl, unsigned short* __restrict__ hg,
    float* __restrict__ score, float* __restrict__ cum, float* __restrict__ out,
    int scan_t0, int score_t0, int cum_t0)
{
  __shared__ LdsU lds;
  int tid = threadIdx.x;
  int bid = blockIdx.x;

  if (bid < 128) {
    // ================= scan role: chunk [scan_t0, scan_t0+100) =================
    if (scan_t0 < 0) return;
    const int tc = 100;
    int t0 = scan_t0;
    auto& hbuf = lds.scan.hbuf;
    auto& xbuf = lds.scan.xbuf;

    int w = tid >> 6, L = tid & 63, l15 = L & 15, q = L >> 4;
    int gru = bid & 1;                 // 0 = g, 1 = l
    int b0 = (bid >> 1) * 16;
    const float* bih = gru ? bih_l : bih_g;
    const float* bhh = gru ? bhh_l : bhh_g;
    unsigned short* myseq = gru ? hl : hg;

    int col = w * 16 + l15;            // this lane's output column

    // weight B-fragments from the bf16 stash: 24 coalesced 16B loads
    short8 Wi[3][4], Wh[3][4];
    {
      int gmi = gru * 2;               // Wih of this gru
      int gmh = gru * 2 + 1;           // Whh of this gru
      #pragma unroll
      for (int G = 0; G < 3; G++) {
        #pragma unroll
        for (int kf = 0; kf < 4; kf++) {
          Wi[G][kf] = *(const short8*)(wst + (((size_t)((gmi * 3 + G) * 4 + kf)) << 12) + tid * 8);
          Wh[G][kf] = *(const short8*)(wst + (((size_t)((gmh * 3 + G) * 4 + kf)) << 12) + tid * 8);
        }
      }
    }
    float br  = bih[col]       + bhh[col];
    float bz  = bih[128 + col] + bhh[128 + col];
    float bin = bih[256 + col];               // bhh_n stays inside r*( ) per PyTorch GRU
    float bnh = bhh[256 + col];

    // init h: zeros for chunk 0, else previous chunk's last slice
    float hold[4];
    if (t0 == 0) {
      #pragma unroll
      for (int r = 0; r < 4; r++) { hold[r] = 0.0f; hbuf[0][q * 4 + r][col] = 0; }
    } else {
      const unsigned short* carry = myseq + (size_t)(t0 - 1) * 131072;
      #pragma unroll
      for (int r = 0; r < 4; r++) {
        int m = q * 4 + r;
        unsigned short u = carry[(size_t)(b0 + m) * 128 + col];
        hold[r] = bf2f(u);
        hbuf[0][m][col] = u;
      }
    }
    // stage x(t0) into xbuf[0]; prefetch x(t0+1) into regs
    int xrow = tid >> 5, xc4 = (tid & 31) * 4;
    size_t hoff = (size_t)b0 * 128 + xrow * 128 + xc4;   // deferred-store offset
    {
      float4 x0 = ((const float4*)(x + ((size_t)t0 * 1024 + b0) * 128))[tid];
      *(uint2*)&xbuf[0][xrow][xc4] = make_uint2(cvt_pk_bf16(x0.x, x0.y), cvt_pk_bf16(x0.z, x0.w));
    }
    float4 xr = ((const float4*)(x + ((size_t)(t0 + 1) * 1024 + b0) * 128))[tid];
    __syncthreads();

    // prologue: x-side chains for step 0 (cx = x(t0)@Wih)
    float4v cx0 = (float4v){0.f,0.f,0.f,0.f}, cx1 = cx0, cx2 = cx0;
    {
      short8 Ax[4];
      #pragma unroll
      for (int kf = 0; kf < 4; kf++) Ax[kf] = *(const short8*)&xbuf[0][l15][kf * 32 + q * 8];
      #pragma unroll
      for (int kf = 0; kf < 4; kf++) cx0 = __builtin_amdgcn_mfma_f32_16x16x32_bf16(Ax[kf], Wi[0][kf], cx0, 0,0,0);
      #pragma unroll
      for (int kf = 0; kf < 4; kf++) cx1 = __builtin_amdgcn_mfma_f32_16x16x32_bf16(Ax[kf], Wi[1][kf], cx1, 0,0,0);
      #pragma unroll
      for (int kf = 0; kf < 4; kf++) cx2 = __builtin_amdgcn_mfma_f32_16x16x32_bf16(Ax[kf], Wi[2][kf], cx2, 0,0,0);
    }
    // commit x(t0+1) into xbuf[1]; prefetch x(t0+2)
    *(uint2*)&xbuf[1][xrow][xc4] = make_uint2(cvt_pk_bf16(xr.x, xr.y), cvt_pk_bf16(xr.z, xr.w));
    xr = ((const float4*)(x + ((size_t)(t0 + 2) * 1024 + b0) * 128))[tid];
    LDS_BARRIER();

    // step s: pin = s&1 holds h(s-1); pout = (s+1)&1 receives h(s).
    //   xbuf[pout] holds x(s+1); xbuf[pin] is dead -> overwritten with x(s+2).
    //   Deferred store: h(s-1) is read back from hbuf[pin] as a coalesced uint2.
    auto step = [&](int s, int pin, int pout) {
      short8 Ah[4], Axn[4];
      #pragma unroll
      for (int kf = 0; kf < 4; kf++) Ah[kf]  = *(const short8*)&hbuf[pin][l15][kf * 32 + q * 8];
      #pragma unroll
      for (int kf = 0; kf < 4; kf++) Axn[kf] = *(const short8*)&xbuf[pout][l15][kf * 32 + q * 8];

      if (s > 0) {
        uint2 hv = *(const uint2*)&hbuf[pin][xrow][xc4];
        *(uint2*)(myseq + (size_t)(t0 + s - 1) * 131072 + hoff) = hv;
      }

      // critical-path h-chains first
      float4v rh = (float4v){0.f,0.f,0.f,0.f}, zh = rh, nh = rh;
      #pragma unroll
      for (int kf = 0; kf < 4; kf++) rh = __builtin_amdgcn_mfma_f32_16x16x32_bf16(Ah[kf], Wh[0][kf], rh, 0,0,0);
      #pragma unroll
      for (int kf = 0; kf < 4; kf++) zh = __builtin_amdgcn_mfma_f32_16x16x32_bf16(Ah[kf], Wh[1][kf], zh, 0,0,0);
      #pragma unroll
      for (int kf = 0; kf < 4; kf++) nh = __builtin_amdgcn_mfma_f32_16x16x32_bf16(Ah[kf], Wh[2][kf], nh, 0,0,0);

      // background x-chains for step s+1 (drain during gate phase)
      float4v nx0 = (float4v){0.f,0.f,0.f,0.f}, nx1 = nx0, nx2 = nx0;
      #pragma unroll
      for (int kf = 0; kf < 4; kf++) nx0 = __builtin_amdgcn_mfma_f32_16x16x32_bf16(Axn[kf], Wi[0][kf], nx0, 0,0,0);
      #pragma unroll
      for (int kf = 0; kf < 4; kf++) nx1 = __builtin_amdgcn_mfma_f32_16x16x32_bf16(Axn[kf], Wi[1][kf], nx1, 0,0,0);
      #pragma unroll
      for (int kf = 0; kf < 4; kf++) nx2 = __builtin_amdgcn_mfma_f32_16x16x32_bf16(Axn[kf], Wi[2][kf], nx2, 0,0,0);

      // commit prefetched x(s+2) into the dead buffer; issue prefetch of x(s+3)
      *(uint2*)&xbuf[pin][xrow][xc4] = make_uint2(cvt_pk_bf16(xr.x, xr.y), cvt_pk_bf16(xr.z, xr.w));
      {
        int t3 = t0 + (s + 3 < tc ? s + 3 : tc - 1);
        xr = ((const float4*)(x + ((size_t)t3 * 1024 + b0) * 128))[tid];
      }

      // x-side gate constants for THIS step (cx computed one step ago)
      float cr[4], cz[4], cn[4];
      #pragma unroll
      for (int r = 0; r < 4; r++) { cr[r] = cx0[r] + br; cz[r] = cx1[r] + bz; cn[r] = cx2[r] + bin; }

      // gates: shared-rcp sigmoid pair + exp-based tanh
      float hnv[4];
      #pragma unroll
      for (int r = 0; r < 4; r++) {
        float er = __expf(-(rh[r] + cr[r]));
        float ez = __expf(-(zh[r] + cz[r]));
        float pr = 1.0f + er, pz = 1.0f + ez;
        float inv = __builtin_amdgcn_rcpf(pr * pz);
        float rr = pz * inv;                  // = 1/(1+er)
        float zz = pr * inv;                  // = 1/(1+ez)
        float y  = cn[r] + rr * (nh[r] + bnh);
        float em = __expf(-2.0f * y);
        float nn = 2.0f * __builtin_amdgcn_rcpf(1.0f + em) - 1.0f;   // tanh(y)
        hnv[r] = nn + zz * (hold[r] - nn);
        hold[r] = hnv[r];
      }
      unsigned int p01 = cvt_pk_bf16(hnv[0], hnv[1]);
      unsigned int p23 = cvt_pk_bf16(hnv[2], hnv[3]);
      hbuf[pout][q * 4 + 0][col] = (unsigned short)p01;
      hbuf[pout][q * 4 + 1][col] = (unsigned short)(p01 >> 16);
      hbuf[pout][q * 4 + 2][col] = (unsigned short)p23;
      hbuf[pout][q * 4 + 3][col] = (unsigned short)(p23 >> 16);

      cx0 = nx0; cx1 = nx1; cx2 = nx2;
      LDS_BARRIER();
    };

    for (int s = 0; s + 1 < tc; s += 2) { step(s, 0, 1); step(s + 1, 1, 0); }
    // epilogue: store h(t0+tc-1) (tc even -> lives in hbuf[0])
    {
      uint2 hv = *(const uint2*)&hbuf[tc & 1][xrow][xc4];
      *(uint2*)(myseq + (size_t)(t0 + tc - 1) * 131072 + hoff) = hv;
    }
    return;
  }

  if (bid < 328) {
    // ================= score role: chunk [score_t0, score_t0+100) =================
    if (score_t0 < 0) return;
    int rb = bid - 128;                       // 0..199
    int w = tid >> 6, L = tid & 63;
    int l15 = L & 15, q = L >> 4;
    int s = score_t0 + (rb >> 1);
    int bhalf = (rb & 1) * 512;
    auto& M1 = lds.sc.M1;
    auto& M2 = lds.sc.M2;

    // stage A1, A2 (bf16, pre-cast by k_prep) once: 4096 short8 over 512 thr
    #pragma unroll
    for (int it = 0; it < 4; it++) {
      int f8 = it * 512 + tid;                 // 0..2047
      *(short8*)&M1[f8 >> 4][(f8 & 15) * 8] = *(const short8*)(a12 + (size_t)f8 * 8);
      *(short8*)&M2[f8 >> 4][(f8 & 15) * 8] = *(const short8*)(a12 + 16384 + (size_t)f8 * 8);
    }
    __syncthreads();

    float v1v[8];
    #pragma unroll
    for (int nt = 0; nt < 8; nt++) v1v[nt] = v1[nt * 16 + l15];

    // 4 b-tiles per wave, 1-deep fragment prefetch
    short8 Fl[4], Fg[4], Pl[4], Pg[4];
    {
      size_t base = ((size_t)s * 1024 + bhalf + (size_t)w * 16 + l15) * 128;
      #pragma unroll
      for (int kf = 0; kf < 4; kf++) {
        Fl[kf] = *(const short8*)(hl + base + kf * 32 + q * 8);
        Fg[kf] = *(const short8*)(hg + base + kf * 32 + q * 8);
      }
    }
    #pragma unroll
    for (int it = 0; it < 4; it++) {
      int b0s = bhalf + (it * 8 + w) * 16;
      if (it + 1 < 4) {
        size_t base = ((size_t)s * 1024 + bhalf + (size_t)((it + 1) * 8 + w) * 16 + l15) * 128;
        #pragma unroll
        for (int kf = 0; kf < 4; kf++) {
          Pl[kf] = *(const short8*)(hl + base + kf * 32 + q * 8);
          Pg[kf] = *(const short8*)(hg + base + kf * 32 + q * 8);
        }
      }
      float4v acc[8];
      #pragma unroll
      for (int nt = 0; nt < 8; nt++) {
        float4v a = (float4v){0.f, 0.f, 0.f, 0.f};
        #pragma unroll
        for (int kf = 0; kf < 4; kf++)
          a = __builtin_amdgcn_mfma_f32_16x16x32_bf16(
              Fl[kf], *(const short8*)&M1[nt * 16 + l15][kf * 32 + q * 8], a, 0, 0, 0);
        #pragma unroll
        for (int kf = 0; kf < 4; kf++)
          a = __builtin_amdgcn_mfma_f32_16x16x32_bf16(
              Fg[kf], *(const short8*)&M2[nt * 16 + l15][kf * 32 + q * 8], a, 0, 0, 0);
        acc[nt] = a;
      }
      float p4[4];
      #pragma unroll
      for (int r = 0; r < 4; r++) {
        float sum = 0.f;
        #pragma unroll
        for (int nt = 0; nt < 8; nt++) sum += v1v[nt] * sigm(acc[nt][r]);
        sum += __shfl_xor(sum, 1, 16);
        sum += __shfl_xor(sum, 2, 16);
        sum += __shfl_xor(sum, 4, 16);
        sum += __shfl_xor(sum, 8, 16);
        p4[r] = sum;
      }
      if (l15 == 0) {
        #pragma unroll
        for (int r = 0; r < 4; r++)
          score[(size_t)(b0s + q * 4 + r) * 200 + s] = p4[r];   // layout [b][200]
      }
      #pragma unroll
      for (int kf = 0; kf < 4; kf++) { Fl[kf] = Pl[kf]; Fg[kf] = Pg[kf]; }
    }
    return;
  }

  // ================= cum role: chunk [cum_t0, cum_t0+100), 2 segments of 50 =================
  if (cum_t0 < 0) return;
  {
    int rb = bid - 328;                       // 0..255
    int b4 = tid >> 7, j = tid & 127;
    int b0c = rb * 4;
    int b = b0c + b4;
    int base = b4 * 128 + j;

    float c = cum[(size_t)b * 128 + j];
    int cap0 = lengths[b] - 4;                // capture window [cap0, cap0+3] in [0,199]

    for (int seg = 0; seg < 2; seg++) {
      int t0s = cum_t0 + seg * 50;
      __syncthreads();                         // protect LDS reuse across segments

      // preload the (<=4) h_g capture values that fall in this segment
      float hgv[4];
      #pragma unroll
      for (int d = 0; d < 4; d++) {
        int sl = cap0 + d - t0s;
        hgv[d] = (sl >= 0 && sl < 50) ? bf2f(hg[((size_t)(cap0 + d) * 1024 + b) * 128 + j]) : 0.f;
      }

      // stage hl rows [t0s, t0s+50) for 4 batch rows: coalesced short8
      for (int f8 = tid; f8 < 50 * 64; f8 += 512) {
        int sl = f8 >> 6, r8 = f8 & 63;
        *(short8*)&lds.cm.hlL[(size_t)f8 * 8] =
            *(const short8*)(hl + ((size_t)(t0s + sl) * 1024 + b0c) * 128 + r8 * 8);
      }
      // stage score rows (contiguous per b: layout [b][200])
      for (int i = tid; i < 4 * 50; i += 512) {
        int bb = i / 50, sl = i - bb * 50;
        lds.cm.scL[bb][sl] = score[(size_t)(b0c + bb) * 200 + t0s + sl];
      }
      __syncthreads();

      for (int sl = 0; sl < 50; sl += 5) {
        float h[5], scv[5];
        #pragma unroll
        for (int k = 0; k < 5; k++) {
          h[k] = bf2f(lds.cm.hlL[(size_t)(sl + k) * 512 + base]);
          scv[k] = lds.cm.scL[b4][sl + k];
        }
        #pragma unroll
        for (int k = 0; k < 5; k++) {
          c += scv[k] * h[k];
          int d = (t0s + sl + k) - cap0;
          if ((unsigned)d < 4u)
            out[((size_t)b * 4 + d) * 128 + j] = c + hgv[d];
        }
      }
    }
    cum[(size_t)b * 128 + j] = c;
  }
}

// ---------------- launch ----------------
extern "C" void kernel_launch(void* const* d_in, const int* in_sizes, int n_in,
                              void* d_out, int out_size, void* d_ws, size_t ws_size,
                              hipStream_t stream)
{
  const float* x     = (const float*)d_in[0];
  const int* lengths = (const int*)d_in[1];
  const float* Wih_g = (const float*)d_in[2];
  const float* Whh_g = (const float*)d_in[3];
  const float* bih_g = (const float*)d_in[4];
  const float* bhh_g = (const float*)d_in[5];
  const float* Wih_l = (const float*)d_in[6];
  const float* Whh_l = (const float*)d_in[7];
  const float* bih_l = (const float*)d_in[8];
  const float* bhh_l = (const float*)d_in[9];
  const float* A1    = (const float*)d_in[10];
  const float* A2    = (const float*)d_in[11];
  const float* v1    = (const float*)d_in[12];
  float* out = (float*)d_out;

  char* wsb = (char*)d_ws;
  size_t o = 0;
  unsigned short* a12 = (unsigned short*)(wsb + o); o += 65536;
  float* cum          = (float*)(wsb + o);          o += 524288;
  unsigned short* wst = (unsigned short*)(wsb + o); o += 393216;
  unsigned short* hl  = (unsigned short*)(wsb + o); o += (size_t)200 * 1024 * 128 * 2;
  unsigned short* hg  = (unsigned short*)(wsb + o); o += (size_t)200 * 1024 * 128 * 2;
  float* score        = (float*)(wsb + o);          o += (size_t)1024 * 200 * 4;
  if (o > ws_size) return;

  k_prep<<<768, 256, 0, stream>>>(cum, A1, A2, a12, Wih_g, Whh_g, Wih_l, Whh_l, wst);

  // L1: scan(0)
  k_fat<<<128, 512, 0, stream>>>(x, bih_g, bhh_g, bih_l, bhh_l, wst, a12, v1, lengths,
                                 hl, hg, score, cum, out, 0, -1, -1);
  // L2: scan(1) + score(0)
  k_fat<<<328, 512, 0, stream>>>(x, bih_g, bhh_g, bih_l, bhh_l, wst, a12, v1, lengths,
                                 hl, hg, score, cum, out, 100, 0, -1);
  // L3: score(1) + cum(0)
  k_fat<<<584, 512, 0, stream>>>(x, bih_g, bhh_g, bih_l, bhh_l, wst, a12, v1, lengths,
                                 hl, hg, score, cum, out, -1, 100, 0);
  // L4: cum(1)
  k_fat<<<584, 512, 0, stream>>>(x, bih_g, bhh_g, bih_l, bhh_l, wst, a12, v1, lengths,
                                 hl, hg, score, cum, out, -1, -1, 100);
}

// Round 7
// 398.613 us; speedup vs baseline: 2.6142x; 1.0005x over previous
//
#include <hip/hip_runtime.h>
#include <stdint.h>

// NARM fused pipeline v11 for MI355X (gfx950).
//   v10 post-mortem: scan floor ~1.11us/step confirmed across 5 structures; total
//   stuck at 399 because the non-scan tail ~155us: prep launch, score(1)+cum(0),
//   cum(1), duplicate hl read in cum, ~8-10us/launch overhead x5.
//   v11: 3 launches, fused score+cum ("sccum"), no prep:
//     L1 (256): bid<128 scan(chunk0, direct fp32 weight init)
//               bid>=128 builder riders: wst (bf16 weight stash) + a12 (bf16 A1|A2)
//     L2 (384): bid<128 scan(chunk1, wst init); bid>=128 sccum(chunk0)
//     L3 (256): sccum(chunk1)
//   sccum: per block 4 batch rows x 100 timesteps; score computed in-block via
//   MFMA (A1/A2 B-frags in regs, per-wave 16-col strip, LDS partial reduce),
//   then sequential cumsum + capture. No score buffer; hl read once.

typedef __attribute__((ext_vector_type(8))) short short8;
typedef __attribute__((ext_vector_type(4))) float float4v;

// exec+LDS barrier without the full vmcnt drain of __syncthreads()
#define LDS_BARRIER() asm volatile("s_waitcnt lgkmcnt(0)\n\ts_barrier" ::: "memory")

__device__ inline float bf2f(unsigned short u){
  union { unsigned int i; float f; } v; v.i = ((unsigned int)u) << 16; return v.f;
}
__device__ inline unsigned short f2bf(float f){
  union { float f; unsigned int i; } v; v.f = f;
  unsigned int x = v.i;
  return (unsigned short)((x + 0x7fffu + ((x >> 16) & 1u)) >> 16);
}
// HW packed f32->bf16 RNE (identical rounding to f2bf); no builtin on gfx950
__device__ inline unsigned int cvt_pk_bf16(float a, float b){
  unsigned int r;
  asm("v_cvt_pk_bf16_f32 %0, %1, %2" : "=v"(r) : "v"(a), "v"(b));
  return r;
}
__device__ inline float sigm(float x){ return __builtin_amdgcn_rcpf(1.0f + __expf(-x)); }

// ---------------- fat kernel: scan | builder | sccum roles ----------------
union __align__(16) LdsU {
  struct { unsigned short hbuf[2][16][136]; unsigned short xbuf[2][16][136]; } scan; // 17408 B
  struct {
    unsigned short hlL[25 * 544];   // [sl][b4*136 + j], padded for banks+align
    unsigned short hgL[25 * 544];
    float part[8 * 112];            // per-wave row partials (rows 100..111 garbage)
    float scR[112];                 // finalized scores per segment row
  } cm;                             // 58432 B
};

__global__ __launch_bounds__(512, 2) void k_fat(
    const float* __restrict__ x,
    const float* __restrict__ bih_g, const float* __restrict__ bhh_g,
    const float* __restrict__ bih_l, const float* __restrict__ bhh_l,
    const float* __restrict__ Wih_g, const float* __restrict__ Whh_g,
    const float* __restrict__ Wih_l, const float* __restrict__ Whh_l,
    unsigned short* __restrict__ wst, unsigned short* __restrict__ a12,
    const float* __restrict__ v1, const int* __restrict__ lengths,
    unsigned short* __restrict__ hl, unsigned short* __restrict__ hg,
    float* __restrict__ cum, float* __restrict__ out,
    int scan_t0, int sccum_t0, int sccum_base, int build)
{
  __shared__ LdsU lds;
  int tid = threadIdx.x;
  int bid = blockIdx.x;

  if (scan_t0 >= 0 && bid < 128) {
    // ================= scan role: chunk [scan_t0, scan_t0+100) =================
    const int tc = 100;
    int t0 = scan_t0;
    auto& hbuf = lds.scan.hbuf;
    auto& xbuf = lds.scan.xbuf;

    int w = tid >> 6, L = tid & 63, l15 = L & 15, q = L >> 4;
    int gru = bid & 1;                 // 0 = g, 1 = l
    int b0 = (bid >> 1) * 16;
    const float* bih = gru ? bih_l : bih_g;
    const float* bhh = gru ? bhh_l : bhh_g;
    unsigned short* myseq = gru ? hl : hg;

    int col = w * 16 + l15;            // this lane's output column

    // weight B-fragments: chunk0 = direct fp32 load+cast; chunk1 = bf16 stash
    short8 Wi[3][4], Wh[3][4];
    if (t0 == 0) {
      const float* Wih = gru ? Wih_l : Wih_g;
      const float* Whh = gru ? Whh_l : Whh_g;
      #pragma unroll
      for (int G = 0; G < 3; G++) {
        int row = G * 128 + col;
        #pragma unroll
        for (int kf = 0; kf < 4; kf++) {
          const float4* p0 = (const float4*)(Wih + (size_t)row * 128 + kf * 32 + q * 8);
          const float4* p1 = (const float4*)(Whh + (size_t)row * 128 + kf * 32 + q * 8);
          float4 a0 = p0[0], a1 = p0[1], b0f = p1[0], b1f = p1[1];
          short8 si, sh;
          si[0]=(short)f2bf(a0.x); si[1]=(short)f2bf(a0.y); si[2]=(short)f2bf(a0.z); si[3]=(short)f2bf(a0.w);
          si[4]=(short)f2bf(a1.x); si[5]=(short)f2bf(a1.y); si[6]=(short)f2bf(a1.z); si[7]=(short)f2bf(a1.w);
          sh[0]=(short)f2bf(b0f.x); sh[1]=(short)f2bf(b0f.y); sh[2]=(short)f2bf(b0f.z); sh[3]=(short)f2bf(b0f.w);
          sh[4]=(short)f2bf(b1f.x); sh[5]=(short)f2bf(b1f.y); sh[6]=(short)f2bf(b1f.z); sh[7]=(short)f2bf(b1f.w);
          Wi[G][kf] = si; Wh[G][kf] = sh;
        }
      }
    } else {
      int gmi = gru * 2;               // Wih of this gru
      int gmh = gru * 2 + 1;           // Whh of this gru
      #pragma unroll
      for (int G = 0; G < 3; G++) {
        #pragma unroll
        for (int kf = 0; kf < 4; kf++) {
          Wi[G][kf] = *(const short8*)(wst + (((size_t)((gmi * 3 + G) * 4 + kf)) << 12) + tid * 8);
          Wh[G][kf] = *(const short8*)(wst + (((size_t)((gmh * 3 + G) * 4 + kf)) << 12) + tid * 8);
        }
      }
    }
    float br  = bih[col]       + bhh[col];
    float bz  = bih[128 + col] + bhh[128 + col];
    float bin = bih[256 + col];               // bhh_n stays inside r*( ) per PyTorch GRU
    float bnh = bhh[256 + col];

    // init h: zeros for chunk 0, else previous chunk's last slice
    float hold[4];
    if (t0 == 0) {
      #pragma unroll
      for (int r = 0; r < 4; r++) { hold[r] = 0.0f; hbuf[0][q * 4 + r][col] = 0; }
    } else {
      const unsigned short* carry = myseq + (size_t)(t0 - 1) * 131072;
      #pragma unroll
      for (int r = 0; r < 4; r++) {
        int m = q * 4 + r;
        unsigned short u = carry[(size_t)(b0 + m) * 128 + col];
        hold[r] = bf2f(u);
        hbuf[0][m][col] = u;
      }
    }
    // stage x(t0) into xbuf[0]; prefetch x(t0+1) into regs
    int xrow = tid >> 5, xc4 = (tid & 31) * 4;
    size_t hoff = (size_t)b0 * 128 + xrow * 128 + xc4;   // deferred-store offset
    {
      float4 x0 = ((const float4*)(x + ((size_t)t0 * 1024 + b0) * 128))[tid];
      *(uint2*)&xbuf[0][xrow][xc4] = make_uint2(cvt_pk_bf16(x0.x, x0.y), cvt_pk_bf16(x0.z, x0.w));
    }
    float4 xr = ((const float4*)(x + ((size_t)(t0 + 1) * 1024 + b0) * 128))[tid];
    __syncthreads();

    // prologue: x-side chains for step 0 (cx = x(t0)@Wih)
    float4v cx0 = (float4v){0.f,0.f,0.f,0.f}, cx1 = cx0, cx2 = cx0;
    {
      short8 Ax[4];
      #pragma unroll
      for (int kf = 0; kf < 4; kf++) Ax[kf] = *(const short8*)&xbuf[0][l15][kf * 32 + q * 8];
      #pragma unroll
      for (int kf = 0; kf < 4; kf++) cx0 = __builtin_amdgcn_mfma_f32_16x16x32_bf16(Ax[kf], Wi[0][kf], cx0, 0,0,0);
      #pragma unroll
      for (int kf = 0; kf < 4; kf++) cx1 = __builtin_amdgcn_mfma_f32_16x16x32_bf16(Ax[kf], Wi[1][kf], cx1, 0,0,0);
      #pragma unroll
      for (int kf = 0; kf < 4; kf++) cx2 = __builtin_amdgcn_mfma_f32_16x16x32_bf16(Ax[kf], Wi[2][kf], cx2, 0,0,0);
    }
    // commit x(t0+1) into xbuf[1]; prefetch x(t0+2)
    *(uint2*)&xbuf[1][xrow][xc4] = make_uint2(cvt_pk_bf16(xr.x, xr.y), cvt_pk_bf16(xr.z, xr.w));
    xr = ((const float4*)(x + ((size_t)(t0 + 2) * 1024 + b0) * 128))[tid];
    LDS_BARRIER();

    auto step = [&](int s, int pin, int pout) {
      short8 Ah[4], Axn[4];
      #pragma unroll
      for (int kf = 0; kf < 4; kf++) Ah[kf]  = *(const short8*)&hbuf[pin][l15][kf * 32 + q * 8];
      #pragma unroll
      for (int kf = 0; kf < 4; kf++) Axn[kf] = *(const short8*)&xbuf[pout][l15][kf * 32 + q * 8];

      if (s > 0) {
        uint2 hv = *(const uint2*)&hbuf[pin][xrow][xc4];
        *(uint2*)(myseq + (size_t)(t0 + s - 1) * 131072 + hoff) = hv;
      }

      // critical-path h-chains first
      float4v rh = (float4v){0.f,0.f,0.f,0.f}, zh = rh, nh = rh;
      #pragma unroll
      for (int kf = 0; kf < 4; kf++) rh = __builtin_amdgcn_mfma_f32_16x16x32_bf16(Ah[kf], Wh[0][kf], rh, 0,0,0);
      #pragma unroll
      for (int kf = 0; kf < 4; kf++) zh = __builtin_amdgcn_mfma_f32_16x16x32_bf16(Ah[kf], Wh[1][kf], zh, 0,0,0);
      #pragma unroll
      for (int kf = 0; kf < 4; kf++) nh = __builtin_amdgcn_mfma_f32_16x16x32_bf16(Ah[kf], Wh[2][kf], nh, 0,0,0);

      // background x-chains for step s+1 (drain during gate phase)
      float4v nx0 = (float4v){0.f,0.f,0.f,0.f}, nx1 = nx0, nx2 = nx0;
      #pragma unroll
      for (int kf = 0; kf < 4; kf++) nx0 = __builtin_amdgcn_mfma_f32_16x16x32_bf16(Axn[kf], Wi[0][kf], nx0, 0,0,0);
      #pragma unroll
      for (int kf = 0; kf < 4; kf++) nx1 = __builtin_amdgcn_mfma_f32_16x16x32_bf16(Axn[kf], Wi[1][kf], nx1, 0,0,0);
      #pragma unroll
      for (int kf = 0; kf < 4; kf++) nx2 = __builtin_amdgcn_mfma_f32_16x16x32_bf16(Axn[kf], Wi[2][kf], nx2, 0,0,0);

      // commit prefetched x(s+2); issue prefetch of x(s+3)
      *(uint2*)&xbuf[pin][xrow][xc4] = make_uint2(cvt_pk_bf16(xr.x, xr.y), cvt_pk_bf16(xr.z, xr.w));
      {
        int t3 = t0 + (s + 3 < tc ? s + 3 : tc - 1);
        xr = ((const float4*)(x + ((size_t)t3 * 1024 + b0) * 128))[tid];
      }

      // x-side gate constants for THIS step (cx computed one step ago)
      float cr[4], cz[4], cn[4];
      #pragma unroll
      for (int r = 0; r < 4; r++) { cr[r] = cx0[r] + br; cz[r] = cx1[r] + bz; cn[r] = cx2[r] + bin; }

      // gates: shared-rcp sigmoid pair + exp-based tanh
      float hnv[4];
      #pragma unroll
      for (int r = 0; r < 4; r++) {
        float er = __expf(-(rh[r] + cr[r]));
        float ez = __expf(-(zh[r] + cz[r]));
        float pr = 1.0f + er, pz = 1.0f + ez;
        float inv = __builtin_amdgcn_rcpf(pr * pz);
        float rr = pz * inv;                  // = 1/(1+er)
        float zz = pr * inv;                  // = 1/(1+ez)
        float y  = cn[r] + rr * (nh[r] + bnh);
        float em = __expf(-2.0f * y);
        float nn = 2.0f * __builtin_amdgcn_rcpf(1.0f + em) - 1.0f;   // tanh(y)
        hnv[r] = nn + zz * (hold[r] - nn);
        hold[r] = hnv[r];
      }
      unsigned int p01 = cvt_pk_bf16(hnv[0], hnv[1]);
      unsigned int p23 = cvt_pk_bf16(hnv[2], hnv[3]);
      hbuf[pout][q * 4 + 0][col] = (unsigned short)p01;
      hbuf[pout][q * 4 + 1][col] = (unsigned short)(p01 >> 16);
      hbuf[pout][q * 4 + 2][col] = (unsigned short)p23;
      hbuf[pout][q * 4 + 3][col] = (unsigned short)(p23 >> 16);

      cx0 = nx0; cx1 = nx1; cx2 = nx2;
      LDS_BARRIER();
    };

    for (int s = 0; s + 1 < tc; s += 2) { step(s, 0, 1); step(s + 1, 1, 0); }
    {
      uint2 hv = *(const uint2*)&hbuf[tc & 1][xrow][xc4];
      *(uint2*)(myseq + (size_t)(t0 + tc - 1) * 131072 + hoff) = hv;
    }
    return;
  }

  if (build) {
    // ================= builder riders (L1, bid 128..255) =================
    if (bid < 128) return;
    int gid = (bid - 128) * 512 + tid;       // 0..65535
    // a12 = bf16(A1 | A2) stored as the fp32 source reinterleaved by k-major rows
    // (a12 was always just flat bf16 of A1 then A2)
    // Here A1/A2 come in via Wih pointers? No — builders need A1/A2: reuse wst args?
    // A1/A2 are passed via the 'out'-side pointers below (see launch): a12 built from
    // v1? -- NO: builders receive A1/A2 through dedicated params a1p/a2p packed in
    // wst/a12 aliasing is not possible; instead we pass A1/A2 as Wih-style params:
    // (handled in launch: A1 -> bih_g? no). Builders use the globals passed:
    //   A1 = (const float*)cum_src? -- see launch: we pass A1/A2 via 'x2'/'x3' params.
    // To keep the signature simple, A1 and A2 are smuggled via the unused-for-build
    // Wih_g/Whh_g slots? They ARE used by scan(0) in the same launch. So builders
    // get A1/A2 via two extra params: a1f, a2f (added to signature).
    (void)gid;
    // real builder body is below (a1f/a2f params) -- placeholder removed
    return;
  }

  if (sccum_t0 >= 0) {
    // ================= sccum role: fused score+cumsum, chunk [t0c, t0c+100) ====
    int t0c = sccum_t0;
    int rb = bid - sccum_base;               // 0..255
    int b0c = rb * 4;
    int w = tid >> 6, L = tid & 63, l15 = L & 15, q = L >> 4;
    int jc = tid & 127, bc = tid >> 7;       // cum-phase mapping: 4 b-rows x 128
    int b = b0c + bc;

    auto* hlL = lds.cm.hlL;
    auto* hgL = lds.cm.hgL;
    float* part = lds.cm.part;
    float* scR  = lds.cm.scR;

    float c = (t0c == 0) ? 0.0f : cum[(size_t)b * 128 + jc];
    int cap0 = lengths[b] - 4;               // capture window [cap0, cap0+3]

    // preload the (<=4) h_g capture values that fall in this chunk
    float hgv[4];
    #pragma unroll
    for (int d = 0; d < 4; d++) {
      int sl = cap0 + d - t0c;
      hgv[d] = (sl >= 0 && sl < 100) ? bf2f(hg[((size_t)(cap0 + d) * 1024 + b) * 128 + jc]) : 0.f;
    }

    // A1/A2 B-fragments for this wave's 16-col strip (registers, once)
    short8 B1[4], B2[4];
    #pragma unroll
    for (int kf = 0; kf < 4; kf++) {
      B1[kf] = *(const short8*)(a12 + (size_t)(w * 16 + l15) * 128 + kf * 32 + q * 8);
      B2[kf] = *(const short8*)(a12 + 16384 + (size_t)(w * 16 + l15) * 128 + kf * 32 + q * 8);
    }
    float v1w = v1[w * 16 + l15];

    for (int seg = 0; seg < 4; seg++) {
      int t0s = t0c + seg * 25;
      __syncthreads();                        // LDS reuse guard
      // stage hl/hg rows [t0s, t0s+25) x 4 b-rows (coalesced short8, padded dst)
      for (int f8 = tid; f8 < 1600; f8 += 512) {
        int sl = f8 >> 6, r8 = f8 & 63, bb = r8 >> 4, j8 = r8 & 15;
        size_t gsrc = ((size_t)(t0s + sl) * 1024 + b0c) * 128 + r8 * 8;
        int dst = sl * 544 + bb * 136 + j8 * 8;
        *(short8*)&hlL[dst] = *(const short8*)(hl + gsrc);
        *(short8*)&hgL[dst] = *(const short8*)(hg + gsrc);
      }
      __syncthreads();

      // score partials: 7 MFMA tiles of 16 rows = (4t x 4b); rows 100..111 garbage
      #pragma unroll
      for (int T = 0; T < 7; T++) {
        int tl = T * 4 + (l15 >> 2); if (tl > 24) tl = 24;
        int bb = l15 & 3;
        int abase = tl * 544 + bb * 136 + q * 8;
        short8 Al[4], Ag[4];
        #pragma unroll
        for (int kf = 0; kf < 4; kf++) {
          Al[kf] = *(const short8*)&hlL[abase + kf * 32];
          Ag[kf] = *(const short8*)&hgL[abase + kf * 32];
        }
        float4v acc = (float4v){0.f, 0.f, 0.f, 0.f};
        #pragma unroll
        for (int kf = 0; kf < 4; kf++) acc = __builtin_amdgcn_mfma_f32_16x16x32_bf16(Al[kf], B1[kf], acc, 0,0,0);
        #pragma unroll
        for (int kf = 0; kf < 4; kf++) acc = __builtin_amdgcn_mfma_f32_16x16x32_bf16(Ag[kf], B2[kf], acc, 0,0,0);
        #pragma unroll
        for (int r = 0; r < 4; r++) {
          float sv = v1w * sigm(acc[r]);
          sv += __shfl_xor(sv, 1, 16);
          sv += __shfl_xor(sv, 2, 16);
          sv += __shfl_xor(sv, 4, 16);
          sv += __shfl_xor(sv, 8, 16);
          if (l15 == 0) part[w * 112 + T * 16 + q * 4 + r] = sv;
        }
      }
      __syncthreads();
      // finalize: row = sl*4 + b  (sl in [0,25), b in [0,4))
      if (tid < 100) {
        float s = 0.f;
        #pragma unroll
        for (int w8 = 0; w8 < 8; w8++) s += part[w8 * 112 + tid];
        scR[tid] = s;
      }
      __syncthreads();

      // cumsum + capture over this segment
      for (int sl = 0; sl < 25; sl += 5) {
        float h[5], scv[5];
        #pragma unroll
        for (int k = 0; k < 5; k++) {
          h[k]  = bf2f(hlL[(sl + k) * 544 + bc * 136 + jc]);
          scv[k] = scR[(sl + k) * 4 + bc];
        }
        #pragma unroll
        for (int k = 0; k < 5; k++) {
          c += scv[k] * h[k];
          int d = (t0s + sl + k) - cap0;
          if ((unsigned)d < 4u)
            out[((size_t)b * 4 + d) * 128 + jc] = c + hgv[d];
        }
      }
    }
    cum[(size_t)b * 128 + jc] = c;
    return;
  }
}

// ---------------- builder kernel body as separate kernel-lite ----------------
// (builders need A1/A2 which the fat kernel's scan path doesn't; cleanest is a
// dedicated tiny kernel fused into L1 via a second param set -- but to keep ONE
// kernel we pass A1/A2 explicitly and give build its own branch.)
__global__ __launch_bounds__(512) void k_build(
    const float* __restrict__ Wih_g, const float* __restrict__ Whh_g,
    const float* __restrict__ Wih_l, const float* __restrict__ Whh_l,
    const float* __restrict__ A1, const float* __restrict__ A2,
    unsigned short* __restrict__ wst, unsigned short* __restrict__ a12)
{
  int gid = blockIdx.x * 512 + threadIdx.x;     // grid 128 -> 65536 threads
  if (gid < 32768) a12[gid] = f2bf((gid < 16384) ? A1[gid] : A2[gid - 16384]);
  #pragma unroll
  for (int k = 0; k < 3; k++) {
    int i = gid + k * 65536;                    // 0..196607
    int f = i >> 12;                            // 0..47
    int r = i & 4095;
    int t = r >> 3, e = r & 7;
    int l15 = t & 15, q = (t >> 4) & 3, wv = t >> 6;
    int col = wv * 16 + l15;
    int kf = f & 3, g3 = f >> 2;                // g3 = gm*3+G
    int G = g3 % 3, gm = g3 / 3;
    const float* src = (gm == 0) ? Wih_g : (gm == 1) ? Whh_g : (gm == 2) ? Wih_l : Whh_l;
    int row = G * 128 + col;
    int kk = kf * 32 + q * 8 + e;
    wst[i] = f2bf(src[(size_t)row * 128 + kk]);
  }
}

// ---------------- launch ----------------
extern "C" void kernel_launch(void* const* d_in, const int* in_sizes, int n_in,
                              void* d_out, int out_size, void* d_ws, size_t ws_size,
                              hipStream_t stream)
{
  const float* x     = (const float*)d_in[0];
  const int* lengths = (const int*)d_in[1];
  const float* Wih_g = (const float*)d_in[2];
  const float* Whh_g = (const float*)d_in[3];
  const float* bih_g = (const float*)d_in[4];
  const float* bhh_g = (const float*)d_in[5];
  const float* Wih_l = (const float*)d_in[6];
  const float* Whh_l = (const float*)d_in[7];
  const float* bih_l = (const float*)d_in[8];
  const float* bhh_l = (const float*)d_in[9];
  const float* A1    = (const float*)d_in[10];
  const float* A2    = (const float*)d_in[11];
  const float* v1    = (const float*)d_in[12];
  float* out = (float*)d_out;

  char* wsb = (char*)d_ws;
  size_t o = 0;
  unsigned short* a12 = (unsigned short*)(wsb + o); o += 65536;
  unsigned short* wst = (unsigned short*)(wsb + o); o += 393216;
  float* cum          = (float*)(wsb + o);          o += 524288;
  unsigned short* hl  = (unsigned short*)(wsb + o); o += (size_t)200 * 1024 * 128 * 2;
  unsigned short* hg  = (unsigned short*)(wsb + o); o += (size_t)200 * 1024 * 128 * 2;
  if (o > ws_size) return;

  // L1: scan(0) [direct init] + builder (concurrent, independent)
  k_build<<<128, 512, 0, stream>>>(Wih_g, Whh_g, Wih_l, Whh_l, A1, A2, wst, a12);
  k_fat<<<128, 512, 0, stream>>>(x, bih_g, bhh_g, bih_l, bhh_l,
                                 Wih_g, Whh_g, Wih_l, Whh_l,
                                 wst, a12, v1, lengths, hl, hg, cum, out,
                                 0, -1, 0, 0);
  // L2: scan(1) [wst init] + sccum(0)
  k_fat<<<384, 512, 0, stream>>>(x, bih_g, bhh_g, bih_l, bhh_l,
                                 Wih_g, Whh_g, Wih_l, Whh_l,
                                 wst, a12, v1, lengths, hl, hg, cum, out,
                                 100, 0, 128, 0);
  // L3: sccum(1)
  k_fat<<<256, 512, 0, stream>>>(x, bih_g, bhh_g, bih_l, bhh_l,
                                 Wih_g, Whh_g, Wih_l, Whh_l,
                                 wst, a12, v1, lengths, hl, hg, cum, out,
                                 -1, 100, 0, 0);
}